// Round 1
// 150.579 us; speedup vs baseline: 1.1920x; 1.1920x over previous
//
#include <hip/hip_runtime.h>
#include <hip/hip_bf16.h>

typedef float f32x4 __attribute__((ext_vector_type(4)));
typedef __bf16 bf16x8 __attribute__((ext_vector_type(8)));

#define AS3(p) ((__attribute__((address_space(3))) void*)(p))
#define AS1(p) ((const __attribute__((address_space(1))) void*)(p))

__device__ __forceinline__ unsigned short f2bf(float f) {
    unsigned u = __float_as_uint(f);
    return (unsigned short)((u + 0x7fffu + ((u >> 16) & 1u)) >> 16);  // RNE
}

__device__ __forceinline__ unsigned long long sort_key(float v, int idx) {
    unsigned ub = __float_as_uint(v);
    unsigned m  = (ub & 0x80000000u) ? ~ub : (ub | 0x80000000u);  // asc map
    return ((unsigned long long)(~m) << 12) | (unsigned)idx;      // desc, stable
}

// ---------------------------------------------------------------------------
// Fused prep: one dispatch.
//   blocks [0,1024):      x fp32 -> bf16
//   blocks [1024,2304):   W1/W2 transpose+convert (64x64 tiles)
//   block  2304:          zero scores accumulator + posg
// ---------------------------------------------------------------------------
__global__ __launch_bounds__(256) void prep_all(
    const float* __restrict__ x, unsigned short* __restrict__ xb,
    const float* __restrict__ W1, unsigned short* __restrict__ W1t,
    const float* __restrict__ W2, unsigned short* __restrict__ W2t,
    float* __restrict__ sc, int* __restrict__ posg)
{
    __shared__ float tile[64][65];
    const int bx = blockIdx.x;
    const int t = threadIdx.x;

    if (bx < 1024) {                       // convert x
        int i = bx * 2048 + t * 8;
        float4 v0 = *(const float4*)(x + i);
        float4 v1 = *(const float4*)(x + i + 4);
        ushort4 o0 = { f2bf(v0.x), f2bf(v0.y), f2bf(v0.z), f2bf(v0.w) };
        ushort4 o1 = { f2bf(v1.x), f2bf(v1.y), f2bf(v1.z), f2bf(v1.w) };
        *(ushort4*)(xb + i)     = o0;
        *(ushort4*)(xb + i + 4) = o1;
        return;
    }
    if (bx == 2304) {                      // zero sc + posg
        float4 z = {0.f, 0.f, 0.f, 0.f};
        int4 zi = {0, 0, 0, 0};
        #pragma unroll
        for (int i = 0; i < 4; ++i) {
            *(float4*)(sc + t * 16 + i * 4)  = z;
            *(int4*)(posg + t * 16 + i * 4)  = zi;
        }
        return;
    }
    // transpose tiles
    int idx = bx - 1024;
    int ty = idx >> 5;                     // 0..39
    int txi = idx & 31;                    // 0..31
    const float* W; unsigned short* Wt; int K, N, by;
    if (ty < 8) { W = W1; Wt = W1t; K = 512;  N = 2048; by = ty; }
    else        { W = W2; Wt = W2t; K = 2048; N = 2048; by = ty - 8; }

    const int col4 = t & 15;
    const int row  = t >> 4;
    #pragma unroll
    for (int i = 0; i < 4; ++i) {
        int r = row + i * 16;
        float4 v = *(const float4*)(W + (size_t)(by * 64 + r) * N + txi * 64 + col4 * 4);
        tile[r][col4 * 4 + 0] = v.x;
        tile[r][col4 * 4 + 1] = v.y;
        tile[r][col4 * 4 + 2] = v.z;
        tile[r][col4 * 4 + 3] = v.w;
    }
    __syncthreads();
    #pragma unroll
    for (int i = 0; i < 4; ++i) {
        int r = row + i * 16;
        ushort4 o = { f2bf(tile[col4 * 4 + 0][r]), f2bf(tile[col4 * 4 + 1][r]),
                      f2bf(tile[col4 * 4 + 2][r]), f2bf(tile[col4 * 4 + 3][r]) };
        *(ushort4*)(Wt + (size_t)(txi * 64 + r) * K + by * 64 + col4 * 4) = o;
    }
}

// ---------------------------------------------------------------------------
// bf16 MFMA GEMM, 128x128 tile, BK=128. (unchanged this round)
// ---------------------------------------------------------------------------
template <int MODE>
__global__ __launch_bounds__(512, 4) void gemm_bf16_mfma(
    const unsigned short* __restrict__ A, const unsigned short* __restrict__ Bt,
    const float* __restrict__ bias, unsigned short* __restrict__ Cbf,
    const float* __restrict__ w3, float* __restrict__ scores,
    int M, int N, int K)
{
    __shared__ unsigned short As[128 * 128];   // 32 KB
    __shared__ unsigned short Bs[128 * 128];   // 32 KB

    const int tid = threadIdx.x;
    const int wave = tid >> 6, lane = tid & 63;
    const int bn = blockIdx.x, bm = blockIdx.y;
    const int wm = (wave & 1) * 64, wn = (wave >> 1) * 32;

    const unsigned short* Ablk = A  + (size_t)(bm * 128) * K;
    const unsigned short* Bblk = Bt + (size_t)(bn * 128) * K;

    const int rl4 = lane >> 4;          // 0..3 (row within 4-row segment)
    const int ch  = lane & 15;          // chunk slot

    f32x4 acc[4][2] = {};

    for (int k0 = 0; k0 < K; k0 += 128) {
        #pragma unroll
        for (int s2 = 0; s2 < 4; ++s2) {        // wave stages A+B rows [wave*16,+16)
            int r0 = wave * 16 + s2 * 4;
            int ra = r0 + rl4;
            int gc = (ch ^ (ra & 15)) * 8;      // swizzled global chunk
            __builtin_amdgcn_global_load_lds(
                AS1(Ablk + (size_t)ra * K + k0 + gc), AS3(As + r0 * 128), 16, 0, 0);
            __builtin_amdgcn_global_load_lds(
                AS1(Bblk + (size_t)ra * K + k0 + gc), AS3(Bs + r0 * 128), 16, 0, 0);
        }
        __syncthreads();

        #pragma unroll
        for (int s = 0; s < 4; ++s) {           // four 16x16x32 k-steps
            const int rsw = ((s * 4 + (lane >> 4)) ^ (lane & 15)) * 8;
            bf16x8 a[4], b[2];
            #pragma unroll
            for (int mt = 0; mt < 4; ++mt)
                a[mt] = *(const bf16x8*)(As + (wm + mt * 16 + (lane & 15)) * 128 + rsw);
            #pragma unroll
            for (int nt = 0; nt < 2; ++nt)
                b[nt] = *(const bf16x8*)(Bs + (wn + nt * 16 + (lane & 15)) * 128 + rsw);
            #pragma unroll
            for (int mt = 0; mt < 4; ++mt)
                #pragma unroll
                for (int nt = 0; nt < 2; ++nt)
                    acc[mt][nt] = __builtin_amdgcn_mfma_f32_16x16x32_bf16(
                        a[mt], b[nt], acc[mt][nt], 0, 0, 0);
        }
        __syncthreads();
    }

    // Epilogue. C/D frag: col = lane&15, row = (lane>>4)*4 + reg  [m89]
    const int cm0 = bm * 128 + wm;
    const int cn0 = bn * 128 + wn;
    const int lc = lane & 15;
    const int lr = (lane >> 4) * 4;

    if (MODE == 0) {
        #pragma unroll
        for (int nt = 0; nt < 2; ++nt) {
            float bv = bias[cn0 + nt * 16 + lc];
            #pragma unroll
            for (int mt = 0; mt < 4; ++mt)
                #pragma unroll
                for (int r = 0; r < 4; ++r) {
                    float v = fmaxf(acc[mt][nt][r] + bv, 0.0f);
                    size_t idx = (size_t)(cm0 + mt * 16 + lr + r) * N + cn0 + nt * 16 + lc;
                    Cbf[idx] = f2bf(v);
                }
        }
    } else {
        float bv[2], w3v[2];
        #pragma unroll
        for (int nt = 0; nt < 2; ++nt) {
            bv[nt]  = bias[cn0 + nt * 16 + lc];
            w3v[nt] = w3[cn0 + nt * 16 + lc];
        }
        #pragma unroll
        for (int mt = 0; mt < 4; ++mt)
            #pragma unroll
            for (int r = 0; r < 4; ++r) {
                float p = 0.0f;
                #pragma unroll
                for (int nt = 0; nt < 2; ++nt)
                    p += fmaxf(acc[mt][nt][r] + bv[nt], 0.0f) * w3v[nt];
                p += __shfl_xor(p, 1);
                p += __shfl_xor(p, 2);
                p += __shfl_xor(p, 4);
                p += __shfl_xor(p, 8);
                if (lc == 0)
                    atomicAdd(&scores[cm0 + mt * 16 + lr + r], p);
            }
    }
}

// ---------------------------------------------------------------------------
// Fused finalize + rank count, 2-D tiled (unchanged this round).
// ---------------------------------------------------------------------------
__global__ __launch_bounds__(256) void rank_count(
    const float* __restrict__ sc, const float* __restrict__ b3,
    float* __restrict__ out_scores, int* __restrict__ posg)
{
    __shared__ unsigned long long kj[256];
    const int t = threadIdx.x;
    const int bi = blockIdx.x, bj = blockIdx.y;
    const int i = bi * 256 + t;
    const float b3v = b3[0];

    {
        int j = bj * 256 + t;
        kj[t] = sort_key(sc[j] + b3v, j);
    }
    float vi = sc[i] + b3v;
    if (bj == 0) out_scores[i] = vi;
    const unsigned long long mykey = sort_key(vi, i);
    __syncthreads();

    int cnt = 0;
    #pragma unroll 32
    for (int j = 0; j < 256; ++j)
        cnt += (kj[j] < mykey) ? 1 : 0;
    atomicAdd(&posg[i], cnt);
}

// ---------------------------------------------------------------------------
// PAV + fill, REDESIGNED for latency (R13):
//  - chunks of 16 (256 lanes): per-lane serial chain 16 deep, values in regs
//    (4x float4 LDS reads, ONE wait), write-through stack w/ register top --
//    the common (always-pool) path touches no LDS inside the chain.
//  - tree merge, 8 pairwise rounds (parallel within round) replaces the
//    thread-0 serial 64-chunk merge. Worst case degenerates to serial (safe).
//  - nb broadcast via LDS (deletes global atomic + agent-scope fences).
//  - plds dropped; gather re-reads posg (L2-hot) so LDS fits 64KB w/ cnt[].
// Region invariant: block-list slot index == element index (1 slot/elem), so
// the end of the last block of region [base,base+W) is element base+W.
// ---------------------------------------------------------------------------
__global__ __launch_bounds__(1024) void pav_fill(
    const float* __restrict__ scores, const float* __restrict__ b3,
    const int* __restrict__ posg, float* __restrict__ rank_out)
{
    constexpr int n = 4096;
    __shared__ __align__(16) unsigned char lds[32768 + 16384 + 8192 + 512];
    double* bsum           = (double*)lds;                     // [4096]
    float*  svals          = (float*)(lds + 32768);            // [4096]
    unsigned short* bstart = (unsigned short*)(lds + 49152);   // [4096]
    unsigned short* cnt    = (unsigned short*)(lds + 57344);   // [256]

    const int tid = threadIdx.x;
    const float b3v = b3[0];

    // ---- scatter scores into sorted order (vectorized, 4/thread) ----
    {
        const int t = tid << 2;
        int4 p4 = *(const int4*)(posg + t);
        float4 s4 = *(const float4*)(scores + t);
        svals[p4.x] = s4.x + b3v;
        svals[p4.y] = s4.y + b3v;
        svals[p4.z] = s4.z + b3v;
        svals[p4.w] = s4.w + b3v;
    }
    __syncthreads();

    // ---- Phase A: per-lane PAV on 16-element chunks, 256 lanes ----
    if (tid < 256) {
        const int base = tid << 4;
        float vv[16];
        *(float4*)(vv + 0)  = *(const float4*)(svals + base + 0);
        *(float4*)(vv + 4)  = *(const float4*)(svals + base + 4);
        *(float4*)(vv + 8)  = *(const float4*)(svals + base + 8);
        *(float4*)(vv + 12) = *(const float4*)(svals + base + 12);
        int sp = 0;
        double tsum = 0.0; int tstart = 0;
        #pragma unroll
        for (int s = 0; s < 16; ++s) {
            const int i = base + s;
            double csum = (double)vv[s] - (double)(n - i);
            int cs = i;
            const int ce = i + 1;
            while (sp > 0 &&
                   tsum * (double)(ce - cs) <= csum * (double)(cs - tstart)) {
                csum += tsum; cs = tstart; --sp;
                if (sp > 0) { tsum = bsum[base + sp - 1]; tstart = bstart[base + sp - 1]; }
            }
            bsum[base + sp] = csum;                 // write-through push
            bstart[base + sp] = (unsigned short)cs;
            tsum = csum; tstart = cs; ++sp;
        }
        cnt[tid] = (unsigned short)sp;
    }
    __syncthreads();

    // ---- Phase B: tree merge, 8 rounds. Merge (left,right) by feeding the
    // right list through the left stack (register-cached top, write-through).
    // In-place safe: push slot <= W+j < next right read slot W+j+1. ----
    #pragma unroll 1
    for (int r = 0; r < 8; ++r) {
        const int m = 128 >> r;
        if (tid < m) {
            const int W  = 16 << r;
            const int L  = tid * (W << 1);    // left element/slot base
            const int Rb = L + W;             // right base
            int sp = cnt[L >> 4];
            const int cr = cnt[Rb >> 4];
            double tsum = bsum[L + sp - 1];
            int tstart = bstart[L + sp - 1];
            for (int j = 0; j < cr; ++j) {
                double csum = bsum[Rb + j];
                int cs = (int)bstart[Rb + j];
                const int ce = (j + 1 < cr) ? (int)bstart[Rb + j + 1] : (Rb + W);
                while (sp > 0 &&
                       tsum * (double)(ce - cs) <= csum * (double)(cs - tstart)) {
                    csum += tsum; cs = tstart; --sp;
                    if (sp > 0) { tsum = bsum[L + sp - 1]; tstart = bstart[L + sp - 1]; }
                }
                bsum[L + sp] = csum;
                bstart[L + sp] = (unsigned short)cs;
                tsum = csum; tstart = cs; ++sp;
            }
            cnt[L >> 4] = (unsigned short)sp;
        }
        __syncthreads();
    }

    // ---- gather: rank[t] = svals[p] - mean(block(p)), coalesced f4 writes ----
    const int nb = (int)cnt[0];
    {
        const int t = tid << 2;
        int4 p4 = *(const int4*)(posg + t);
        float4 o;
        int pa[4] = { p4.x, p4.y, p4.z, p4.w };
        float oa[4];
        #pragma unroll
        for (int e = 0; e < 4; ++e) {
            const int p = pa[e];
            int lo = 0, hi = nb - 1;
            while (lo < hi) {
                int mid = (lo + hi + 1) >> 1;
                if ((int)bstart[mid] <= p) lo = mid; else hi = mid - 1;
            }
            const int bs = (int)bstart[lo];
            const int be = (lo + 1 < nb) ? (int)bstart[lo + 1] : n;
            oa[e] = svals[p] - (float)(bsum[lo] / (double)(be - bs));
        }
        o.x = oa[0]; o.y = oa[1]; o.z = oa[2]; o.w = oa[3];
        *(float4*)(rank_out + t) = o;
    }
}

// ---------------------------------------------------------------------------
extern "C" void kernel_launch(void* const* d_in, const int* in_sizes, int n_in,
                              void* d_out, int out_size, void* d_ws, size_t ws_size,
                              hipStream_t stream) {
    const float* x  = (const float*)d_in[0];
    const float* W1 = (const float*)d_in[1];
    const float* b1 = (const float*)d_in[2];
    const float* W2 = (const float*)d_in[3];
    const float* b2 = (const float*)d_in[4];
    const float* W3 = (const float*)d_in[5];
    const float* b3 = (const float*)d_in[6];
    float* out = (float*)d_out;   // [0,4096): rank, [4096,8192): scores

    const int B = 4096, D_IN = 512, H = 2048;

    char* ws = (char*)d_ws;
    unsigned short* h1  = (unsigned short*)(ws);                    // 16 MB bf16
    unsigned short* xb  = (unsigned short*)(ws + (16u << 20));      //  4 MB bf16
    unsigned short* W1t = (unsigned short*)(ws + (20u << 20));      //  2 MB bf16 [N,K]
    unsigned short* W2t = (unsigned short*)(ws + (22u << 20));      //  8 MB bf16 [N,K]
    float*          sc  = (float*)(ws + (30u << 20));               // 16 KB
    int*            posg= (int*)(ws + (30u << 20) + 16384);         // 16 KB

    // 1) fused prep: convert x, transpose W1/W2, zero sc+posg.
    prep_all<<<2305, 256, 0, stream>>>(x, xb, W1, W1t, W2, W2t, sc, posg);

    // 2) GEMM1: h1 = relu(x @ W1 + b1), bf16. M=4096 N=2048 K=512.
    gemm_bf16_mfma<0><<<dim3(H / 128, B / 128), 512, 0, stream>>>(
        xb, W1t, b1, h1, nullptr, nullptr, B, H, D_IN);
    // 3) GEMM2 fused with layer-3: scores += relu(h1@W2+b2) @ W3.
    gemm_bf16_mfma<1><<<dim3(H / 128, B / 128), 512, 0, stream>>>(
        h1, W2t, b2, nullptr, W3, sc, B, H, H);

    // 4) fused finalize + rank count (256 blocks, keys from sc in-block).
    rank_count<<<dim3(B / 256, B / 256), 256, 0, stream>>>(sc, b3, out + B, posg);
    // 5) PAV + fill (latency-redesigned: reg-chunk PAV + 8-round tree merge).
    pav_fill<<<1, 1024, 0, stream>>>(sc, b3, posg, out);
}

// Round 2
// 149.661 us; speedup vs baseline: 1.1993x; 1.0061x over previous
//
#include <hip/hip_runtime.h>
#include <hip/hip_bf16.h>

typedef float f32x4 __attribute__((ext_vector_type(4)));
typedef __bf16 bf16x8 __attribute__((ext_vector_type(8)));

#define AS3(p) ((__attribute__((address_space(3))) void*)(p))
#define AS1(p) ((const __attribute__((address_space(1))) void*)(p))

__device__ __forceinline__ unsigned short f2bf(float f) {
    unsigned u = __float_as_uint(f);
    return (unsigned short)((u + 0x7fffu + ((u >> 16) & 1u)) >> 16);  // RNE
}

__device__ __forceinline__ unsigned long long sort_key(float v, int idx) {
    unsigned ub = __float_as_uint(v);
    unsigned m  = (ub & 0x80000000u) ? ~ub : (ub | 0x80000000u);  // asc map
    return ((unsigned long long)(~m) << 12) | (unsigned)idx;      // desc, stable
}

// ---------------------------------------------------------------------------
// Fused prep: one dispatch.
//   blocks [0,1024):      x fp32 -> bf16
//   blocks [1024,2304):   W1/W2 transpose+convert (64x64 tiles)
//   block  2304:          zero scores accumulator + posg
// ---------------------------------------------------------------------------
__global__ __launch_bounds__(256) void prep_all(
    const float* __restrict__ x, unsigned short* __restrict__ xb,
    const float* __restrict__ W1, unsigned short* __restrict__ W1t,
    const float* __restrict__ W2, unsigned short* __restrict__ W2t,
    float* __restrict__ sc, int* __restrict__ posg)
{
    __shared__ float tile[64][65];
    const int bx = blockIdx.x;
    const int t = threadIdx.x;

    if (bx < 1024) {                       // convert x
        int i = bx * 2048 + t * 8;
        float4 v0 = *(const float4*)(x + i);
        float4 v1 = *(const float4*)(x + i + 4);
        ushort4 o0 = { f2bf(v0.x), f2bf(v0.y), f2bf(v0.z), f2bf(v0.w) };
        ushort4 o1 = { f2bf(v1.x), f2bf(v1.y), f2bf(v1.z), f2bf(v1.w) };
        *(ushort4*)(xb + i)     = o0;
        *(ushort4*)(xb + i + 4) = o1;
        return;
    }
    if (bx == 2304) {                      // zero sc + posg
        float4 z = {0.f, 0.f, 0.f, 0.f};
        int4 zi = {0, 0, 0, 0};
        #pragma unroll
        for (int i = 0; i < 4; ++i) {
            *(float4*)(sc + t * 16 + i * 4)  = z;
            *(int4*)(posg + t * 16 + i * 4)  = zi;
        }
        return;
    }
    // transpose tiles
    int idx = bx - 1024;
    int ty = idx >> 5;                     // 0..39
    int txi = idx & 31;                    // 0..31
    const float* W; unsigned short* Wt; int K, N, by;
    if (ty < 8) { W = W1; Wt = W1t; K = 512;  N = 2048; by = ty; }
    else        { W = W2; Wt = W2t; K = 2048; N = 2048; by = ty - 8; }

    const int col4 = t & 15;
    const int row  = t >> 4;
    #pragma unroll
    for (int i = 0; i < 4; ++i) {
        int r = row + i * 16;
        float4 v = *(const float4*)(W + (size_t)(by * 64 + r) * N + txi * 64 + col4 * 4);
        tile[r][col4 * 4 + 0] = v.x;
        tile[r][col4 * 4 + 1] = v.y;
        tile[r][col4 * 4 + 2] = v.z;
        tile[r][col4 * 4 + 3] = v.w;
    }
    __syncthreads();
    #pragma unroll
    for (int i = 0; i < 4; ++i) {
        int r = row + i * 16;
        ushort4 o = { f2bf(tile[col4 * 4 + 0][r]), f2bf(tile[col4 * 4 + 1][r]),
                      f2bf(tile[col4 * 4 + 2][r]), f2bf(tile[col4 * 4 + 3][r]) };
        *(ushort4*)(Wt + (size_t)(txi * 64 + r) * K + by * 64 + col4 * 4) = o;
    }
}

// ---------------------------------------------------------------------------
// bf16 MFMA GEMM, 128x128 tile, BK=64, DOUBLE-BUFFERED with counted vmcnt
// across RAW s_barrier (T3+T4: prefetch loads stay in flight through the
// barrier; never drain vmcnt to 0 in the main loop). 512 thr = 8 waves
// (wm 2x64, wn 4x32), LDS 2x32 KB, 2 blocks/CU. T1 XCD swizzle on block id
// (nwg=512, 512%8==0 -> bijective).
// Swizzle: LDS slot (r, c) holds global chunk c^(r&7), c = 16B chunk (8 per
// 128B row). Stage: pre-swizzled GLOBAL src + linear LDS dest (rule #21).
// Frag reads: chunk (s*4+rl4)^(lc&7) -> 2-way bank aliasing only (free, m136).
// MODE 0: C = relu(A@Bt^T+bias) bf16.  MODE 1: fused layer-3 rank-1 epilogue.
// ---------------------------------------------------------------------------
#define GB_WAITV(n) { asm volatile("s_waitcnt vmcnt(" #n ")" ::: "memory"); \
                      __builtin_amdgcn_sched_barrier(0); }
#define GB_BAR()    { __builtin_amdgcn_sched_barrier(0);                    \
                      __builtin_amdgcn_s_barrier();                         \
                      __builtin_amdgcn_sched_barrier(0); }

template <int MODE>
__global__ __launch_bounds__(512, 4) void gemm_bf16_mfma(
    const unsigned short* __restrict__ A, const unsigned short* __restrict__ Bt,
    const float* __restrict__ bias, unsigned short* __restrict__ Cbf,
    const float* __restrict__ w3, float* __restrict__ scores,
    int M, int N, int K)
{
    __shared__ __align__(16) unsigned short As[2][128 * 64];   // 2x16 KB
    __shared__ __align__(16) unsigned short Bs[2][128 * 64];   // 2x16 KB

    const int tid = threadIdx.x;
    const int wave = tid >> 6, lane = tid & 63;

    // T1: XCD-aware block swizzle (bijective: nwg % 8 == 0)
    const unsigned nwg = gridDim.x * gridDim.y;
    const unsigned bid = blockIdx.y * gridDim.x + blockIdx.x;
    const unsigned sbid = (bid & 7u) * (nwg >> 3) + (bid >> 3);
    const int bn = sbid % gridDim.x;
    const int bm = sbid / gridDim.x;

    const int wm = (wave & 1) * 64, wn = (wave >> 1) * 32;

    const unsigned short* Ablk = A  + (size_t)(bm * 128) * K;
    const unsigned short* Bblk = Bt + (size_t)(bn * 128) * K;

    const int rl4 = lane >> 4;          // 0..3
    const int lc  = lane & 15;

    // staging geometry: wave w, lane ln covers rows l*64 + w*8 + (ln>>3),
    // global chunk (ln&7)^(row&7); LDS dest wave-uniform base + lane*16B.
    const int srow = lane >> 3;                    // 0..7
    const int sgc  = ((lane & 7) ^ srow) << 3;     // pre-swizzled src chunk (elems)

    f32x4 acc[4][2] = {};

    const int nt = K >> 6;              // K-tiles of 64 (K in {512, 2048})

    #define GB_STAGE(k0, Ad, Bd)                                               \
        _Pragma("unroll")                                                      \
        for (int l = 0; l < 2; ++l) {                                          \
            const int ra = l * 64 + wave * 8 + srow;                           \
            const int lo = (l * 64 + wave * 8) * 64;                           \
            __builtin_amdgcn_global_load_lds(                                  \
                AS1(Ablk + (size_t)ra * K + (k0) + sgc), AS3((Ad) + lo), 16, 0, 0); \
            __builtin_amdgcn_global_load_lds(                                  \
                AS1(Bblk + (size_t)ra * K + (k0) + sgc), AS3((Bd) + lo), 16, 0, 0); \
        }

    #define GB_COMPUTE(Ab, Bb)                                                 \
        __builtin_amdgcn_s_setprio(1);                                         \
        _Pragma("unroll")                                                      \
        for (int s = 0; s < 2; ++s) {                                          \
            const int rsw = (((s * 4 + rl4) ^ (lc & 7)) << 3);                 \
            bf16x8 a[4], b[2];                                                 \
            _Pragma("unroll")                                                  \
            for (int mt = 0; mt < 4; ++mt)                                     \
                a[mt] = *(const bf16x8*)((Ab) + (wm + mt * 16 + lc) * 64 + rsw);\
            _Pragma("unroll")                                                  \
            for (int nt2 = 0; nt2 < 2; ++nt2)                                  \
                b[nt2] = *(const bf16x8*)((Bb) + (wn + nt2 * 16 + lc) * 64 + rsw);\
            _Pragma("unroll")                                                  \
            for (int mt = 0; mt < 4; ++mt)                                     \
                _Pragma("unroll")                                              \
                for (int nt2 = 0; nt2 < 2; ++nt2)                              \
                    acc[mt][nt2] = __builtin_amdgcn_mfma_f32_16x16x32_bf16(    \
                        a[mt], b[nt2], acc[mt][nt2], 0, 0, 0);                 \
        }                                                                      \
        __builtin_amdgcn_s_setprio(0);

    // prologue: stage tile 0 into buffer 0
    GB_STAGE(0, As[0], Bs[0]);

    // main loop, unrolled x2 so buffer indices are compile-time (nt is even)
    for (int t = 0; t < nt; t += 2) {
        // even tile (buf 0); prefetch t+1 into buf 1
        if (t + 1 < nt) {
            GB_STAGE((t + 1) << 6, As[1], Bs[1]);
            GB_WAITV(4);
        } else {
            GB_WAITV(0);
        }
        GB_BAR();
        GB_COMPUTE(As[0], Bs[0]);
        GB_BAR();

        // odd tile (buf 1); prefetch t+2 into buf 0
        if (t + 1 < nt) {
            if (t + 2 < nt) {
                GB_STAGE((t + 2) << 6, As[0], Bs[0]);
                GB_WAITV(4);
            } else {
                GB_WAITV(0);
            }
            GB_BAR();
            GB_COMPUTE(As[1], Bs[1]);
            GB_BAR();
        }
    }

    #undef GB_STAGE
    #undef GB_COMPUTE

    // Epilogue. C/D frag: col = lane&15, row = (lane>>4)*4 + reg  [m89]
    const int cm0 = bm * 128 + wm;
    const int cn0 = bn * 128 + wn;
    const int lr = (lane >> 4) * 4;

    if (MODE == 0) {
        #pragma unroll
        for (int nt2 = 0; nt2 < 2; ++nt2) {
            float bv = bias[cn0 + nt2 * 16 + lc];
            #pragma unroll
            for (int mt = 0; mt < 4; ++mt)
                #pragma unroll
                for (int r = 0; r < 4; ++r) {
                    float v = fmaxf(acc[mt][nt2][r] + bv, 0.0f);
                    size_t idx = (size_t)(cm0 + mt * 16 + lr + r) * N + cn0 + nt2 * 16 + lc;
                    Cbf[idx] = f2bf(v);
                }
        }
    } else {
        float bv[2], w3v[2];
        #pragma unroll
        for (int nt2 = 0; nt2 < 2; ++nt2) {
            bv[nt2]  = bias[cn0 + nt2 * 16 + lc];
            w3v[nt2] = w3[cn0 + nt2 * 16 + lc];
        }
        #pragma unroll
        for (int mt = 0; mt < 4; ++mt)
            #pragma unroll
            for (int r = 0; r < 4; ++r) {
                float p = 0.0f;
                #pragma unroll
                for (int nt2 = 0; nt2 < 2; ++nt2)
                    p += fmaxf(acc[mt][nt2][r] + bv[nt2], 0.0f) * w3v[nt2];
                p += __shfl_xor(p, 1);
                p += __shfl_xor(p, 2);
                p += __shfl_xor(p, 4);
                p += __shfl_xor(p, 8);
                if (lc == 0)
                    atomicAdd(&scores[cm0 + mt * 16 + lr + r], p);
            }
    }
}

// ---------------------------------------------------------------------------
// Fused finalize + rank count, 2-D tiled (unchanged).
// ---------------------------------------------------------------------------
__global__ __launch_bounds__(256) void rank_count(
    const float* __restrict__ sc, const float* __restrict__ b3,
    float* __restrict__ out_scores, int* __restrict__ posg)
{
    __shared__ unsigned long long kj[256];
    const int t = threadIdx.x;
    const int bi = blockIdx.x, bj = blockIdx.y;
    const int i = bi * 256 + t;
    const float b3v = b3[0];

    {
        int j = bj * 256 + t;
        kj[t] = sort_key(sc[j] + b3v, j);
    }
    float vi = sc[i] + b3v;
    if (bj == 0) out_scores[i] = vi;
    const unsigned long long mykey = sort_key(vi, i);
    __syncthreads();

    int cnt = 0;
    #pragma unroll 32
    for (int j = 0; j < 256; ++j)
        cnt += (kj[j] < mykey) ? 1 : 0;
    atomicAdd(&posg[i], cnt);
}

// ---------------------------------------------------------------------------
// PAV + fill (R13 latency redesign, verified R1: reg-chunk PAV + tree merge).
// ---------------------------------------------------------------------------
__global__ __launch_bounds__(1024) void pav_fill(
    const float* __restrict__ scores, const float* __restrict__ b3,
    const int* __restrict__ posg, float* __restrict__ rank_out)
{
    constexpr int n = 4096;
    __shared__ __align__(16) unsigned char lds[32768 + 16384 + 8192 + 512];
    double* bsum           = (double*)lds;                     // [4096]
    float*  svals          = (float*)(lds + 32768);            // [4096]
    unsigned short* bstart = (unsigned short*)(lds + 49152);   // [4096]
    unsigned short* cnt    = (unsigned short*)(lds + 57344);   // [256]

    const int tid = threadIdx.x;
    const float b3v = b3[0];

    // ---- scatter scores into sorted order (vectorized, 4/thread) ----
    {
        const int t = tid << 2;
        int4 p4 = *(const int4*)(posg + t);
        float4 s4 = *(const float4*)(scores + t);
        svals[p4.x] = s4.x + b3v;
        svals[p4.y] = s4.y + b3v;
        svals[p4.z] = s4.z + b3v;
        svals[p4.w] = s4.w + b3v;
    }
    __syncthreads();

    // ---- Phase A: per-lane PAV on 16-element chunks, 256 lanes ----
    if (tid < 256) {
        const int base = tid << 4;
        float vv[16];
        *(float4*)(vv + 0)  = *(const float4*)(svals + base + 0);
        *(float4*)(vv + 4)  = *(const float4*)(svals + base + 4);
        *(float4*)(vv + 8)  = *(const float4*)(svals + base + 8);
        *(float4*)(vv + 12) = *(const float4*)(svals + base + 12);
        int sp = 0;
        double tsum = 0.0; int tstart = 0;
        #pragma unroll
        for (int s = 0; s < 16; ++s) {
            const int i = base + s;
            double csum = (double)vv[s] - (double)(n - i);
            int cs = i;
            const int ce = i + 1;
            while (sp > 0 &&
                   tsum * (double)(ce - cs) <= csum * (double)(cs - tstart)) {
                csum += tsum; cs = tstart; --sp;
                if (sp > 0) { tsum = bsum[base + sp - 1]; tstart = bstart[base + sp - 1]; }
            }
            bsum[base + sp] = csum;                 // write-through push
            bstart[base + sp] = (unsigned short)cs;
            tsum = csum; tstart = cs; ++sp;
        }
        cnt[tid] = (unsigned short)sp;
    }
    __syncthreads();

    // ---- Phase B: tree merge, 8 rounds ----
    #pragma unroll 1
    for (int r = 0; r < 8; ++r) {
        const int m = 128 >> r;
        if (tid < m) {
            const int W  = 16 << r;
            const int L  = tid * (W << 1);    // left element/slot base
            const int Rb = L + W;             // right base
            int sp = cnt[L >> 4];
            const int cr = cnt[Rb >> 4];
            double tsum = bsum[L + sp - 1];
            int tstart = bstart[L + sp - 1];
            for (int j = 0; j < cr; ++j) {
                double csum = bsum[Rb + j];
                int cs = (int)bstart[Rb + j];
                const int ce = (j + 1 < cr) ? (int)bstart[Rb + j + 1] : (Rb + W);
                while (sp > 0 &&
                       tsum * (double)(ce - cs) <= csum * (double)(cs - tstart)) {
                    csum += tsum; cs = tstart; --sp;
                    if (sp > 0) { tsum = bsum[L + sp - 1]; tstart = bstart[L + sp - 1]; }
                }
                bsum[L + sp] = csum;
                bstart[L + sp] = (unsigned short)cs;
                tsum = csum; tstart = cs; ++sp;
            }
            cnt[L >> 4] = (unsigned short)sp;
        }
        __syncthreads();
    }

    // ---- gather: rank[t] = svals[p] - mean(block(p)), coalesced f4 writes ----
    const int nb = (int)cnt[0];
    {
        const int t = tid << 2;
        int4 p4 = *(const int4*)(posg + t);
        float4 o;
        int pa[4] = { p4.x, p4.y, p4.z, p4.w };
        float oa[4];
        #pragma unroll
        for (int e = 0; e < 4; ++e) {
            const int p = pa[e];
            int lo = 0, hi = nb - 1;
            while (lo < hi) {
                int mid = (lo + hi + 1) >> 1;
                if ((int)bstart[mid] <= p) lo = mid; else hi = mid - 1;
            }
            const int bs = (int)bstart[lo];
            const int be = (lo + 1 < nb) ? (int)bstart[lo + 1] : n;
            oa[e] = svals[p] - (float)(bsum[lo] / (double)(be - bs));
        }
        o.x = oa[0]; o.y = oa[1]; o.z = oa[2]; o.w = oa[3];
        *(float4*)(rank_out + t) = o;
    }
}

// ---------------------------------------------------------------------------
extern "C" void kernel_launch(void* const* d_in, const int* in_sizes, int n_in,
                              void* d_out, int out_size, void* d_ws, size_t ws_size,
                              hipStream_t stream) {
    const float* x  = (const float*)d_in[0];
    const float* W1 = (const float*)d_in[1];
    const float* b1 = (const float*)d_in[2];
    const float* W2 = (const float*)d_in[3];
    const float* b2 = (const float*)d_in[4];
    const float* W3 = (const float*)d_in[5];
    const float* b3 = (const float*)d_in[6];
    float* out = (float*)d_out;   // [0,4096): rank, [4096,8192): scores

    const int B = 4096, D_IN = 512, H = 2048;

    char* ws = (char*)d_ws;
    unsigned short* h1  = (unsigned short*)(ws);                    // 16 MB bf16
    unsigned short* xb  = (unsigned short*)(ws + (16u << 20));      //  4 MB bf16
    unsigned short* W1t = (unsigned short*)(ws + (20u << 20));      //  2 MB bf16 [N,K]
    unsigned short* W2t = (unsigned short*)(ws + (22u << 20));      //  8 MB bf16 [N,K]
    float*          sc  = (float*)(ws + (30u << 20));               // 16 KB
    int*            posg= (int*)(ws + (30u << 20) + 16384);         // 16 KB

    // 1) fused prep: convert x, transpose W1/W2, zero sc+posg.
    prep_all<<<2305, 256, 0, stream>>>(x, xb, W1, W1t, W2, W2t, sc, posg);

    // 2) GEMM1: h1 = relu(x @ W1 + b1), bf16. M=4096 N=2048 K=512.
    gemm_bf16_mfma<0><<<dim3(H / 128, B / 128), 512, 0, stream>>>(
        xb, W1t, b1, h1, nullptr, nullptr, B, H, D_IN);
    // 3) GEMM2 fused with layer-3: scores += relu(h1@W2+b2) @ W3.
    gemm_bf16_mfma<1><<<dim3(H / 128, B / 128), 512, 0, stream>>>(
        h1, W2t, b2, nullptr, W3, sc, B, H, H);

    // 4) fused finalize + rank count (256 blocks, keys from sc in-block).
    rank_count<<<dim3(B / 256, B / 256), 256, 0, stream>>>(sc, b3, out + B, posg);
    // 5) PAV + fill.
    pav_fill<<<1, 1024, 0, stream>>>(sc, b3, posg, out);
}

// Round 4
// 140.345 us; speedup vs baseline: 1.2789x; 1.0664x over previous
//
#include <hip/hip_runtime.h>
#include <hip/hip_bf16.h>

typedef float f32x4 __attribute__((ext_vector_type(4)));
typedef __bf16 bf16x8 __attribute__((ext_vector_type(8)));

#define AS3(p) ((__attribute__((address_space(3))) void*)(p))
#define AS1(p) ((const __attribute__((address_space(1))) void*)(p))

__device__ __forceinline__ unsigned short f2bf(float f) {
    unsigned u = __float_as_uint(f);
    return (unsigned short)((u + 0x7fffu + ((u >> 16) & 1u)) >> 16);  // RNE
}

__device__ __forceinline__ unsigned long long sort_key(float v, int idx) {
    unsigned ub = __float_as_uint(v);
    unsigned m  = (ub & 0x80000000u) ? ~ub : (ub | 0x80000000u);  // asc map
    return ((unsigned long long)(~m) << 12) | (unsigned)idx;      // desc, stable
}

// ---------------------------------------------------------------------------
// Fused prep: one dispatch.
//   blocks [0,1024):      x fp32 -> bf16
//   blocks [1024,2304):   W1/W2 transpose+convert (64x64 tiles)
//   block  2304:          zero scores accumulator + posg
// ---------------------------------------------------------------------------
__global__ __launch_bounds__(256) void prep_all(
    const float* __restrict__ x, unsigned short* __restrict__ xb,
    const float* __restrict__ W1, unsigned short* __restrict__ W1t,
    const float* __restrict__ W2, unsigned short* __restrict__ W2t,
    float* __restrict__ sc, int* __restrict__ posg)
{
    __shared__ float tile[64][65];
    const int bx = blockIdx.x;
    const int t = threadIdx.x;

    if (bx < 1024) {                       // convert x
        int i = bx * 2048 + t * 8;
        float4 v0 = *(const float4*)(x + i);
        float4 v1 = *(const float4*)(x + i + 4);
        ushort4 o0 = { f2bf(v0.x), f2bf(v0.y), f2bf(v0.z), f2bf(v0.w) };
        ushort4 o1 = { f2bf(v1.x), f2bf(v1.y), f2bf(v1.z), f2bf(v1.w) };
        *(ushort4*)(xb + i)     = o0;
        *(ushort4*)(xb + i + 4) = o1;
        return;
    }
    if (bx == 2304) {                      // zero sc + posg
        float4 z = {0.f, 0.f, 0.f, 0.f};
        int4 zi = {0, 0, 0, 0};
        #pragma unroll
        for (int i = 0; i < 4; ++i) {
            *(float4*)(sc + t * 16 + i * 4)  = z;
            *(int4*)(posg + t * 16 + i * 4)  = zi;
        }
        return;
    }
    // transpose tiles
    int idx = bx - 1024;
    int ty = idx >> 5;                     // 0..39
    int txi = idx & 31;                    // 0..31
    const float* W; unsigned short* Wt; int K, N, by;
    if (ty < 8) { W = W1; Wt = W1t; K = 512;  N = 2048; by = ty; }
    else        { W = W2; Wt = W2t; K = 2048; N = 2048; by = ty - 8; }

    const int col4 = t & 15;
    const int row  = t >> 4;
    #pragma unroll
    for (int i = 0; i < 4; ++i) {
        int r = row + i * 16;
        float4 v = *(const float4*)(W + (size_t)(by * 64 + r) * N + txi * 64 + col4 * 4);
        tile[r][col4 * 4 + 0] = v.x;
        tile[r][col4 * 4 + 1] = v.y;
        tile[r][col4 * 4 + 2] = v.z;
        tile[r][col4 * 4 + 3] = v.w;
    }
    __syncthreads();
    #pragma unroll
    for (int i = 0; i < 4; ++i) {
        int r = row + i * 16;
        ushort4 o = { f2bf(tile[col4 * 4 + 0][r]), f2bf(tile[col4 * 4 + 1][r]),
                      f2bf(tile[col4 * 4 + 2][r]), f2bf(tile[col4 * 4 + 3][r]) };
        *(ushort4*)(Wt + (size_t)(txi * 64 + r) * K + by * 64 + col4 * 4) = o;
    }
}

// ---------------------------------------------------------------------------
// bf16 MFMA GEMM, 256x128 tile, BK=64, TRIPLE-BUFFERED, prefetch distance 2,
// steady-state s_waitcnt vmcnt(6) (T4: never drains in main loop), ONE raw
// s_barrier per K-tile placed BEFORE the prefetch issue.
// Race analysis: tile t's buffer is overwritten by loads issued at tile t+1
// (for t+3). Every wave's tile-t ds_reads are lgkm-complete before its
// phase-2 MFMAs issue (compiler-inserted waits), hence before it arrives at
// tile t+1's barrier; the overwrite issue is after that barrier. Safe.
// 512 thr = 8 waves (4M x 2N, per-wave 64x64 out), LDS 3x48 KB = 144 KB,
// 1 block/CU (grid 256 = 1/CU exactly). 32 MFMA + 16 ds_read_b128 +
// 6 global_load_lds per tile per thread.
// Swizzle: LDS slot (r,c) holds global chunk c^(r&7), staged via pre-swizzled
// GLOBAL src + linear LDS dest (rule #21); frag reads XOR back -> 2-way bank
// aliasing only (free, m136). T1 XCD swizzle (nwg=256, %8==0, bijective).
// MODE 0: C = relu(A@Bt^T+bias) bf16.  MODE 1: fused layer-3 rank-1 epilogue.
// ---------------------------------------------------------------------------
#define GB_WAITV(n) { asm volatile("s_waitcnt vmcnt(" #n ")" ::: "memory"); \
                      __builtin_amdgcn_sched_barrier(0); }

template <int MODE>
__global__ __launch_bounds__(512, 2) void gemm_bf16_mfma(
    const unsigned short* __restrict__ A, const unsigned short* __restrict__ Bt,
    const float* __restrict__ bias, unsigned short* __restrict__ Cbf,
    const float* __restrict__ w3, float* __restrict__ scores,
    int M, int N, int K)
{
    // 3 buffers; per buffer: A-tile [0, 256*64), B-tile [256*64, 384*64)
    __shared__ __align__(16) unsigned short lds3[3][384 * 64];   // 144 KB
    constexpr int BOFF = 256 * 64;

    const int tid = threadIdx.x;
    const int wave = tid >> 6, lane = tid & 63;

    // T1: XCD-aware block swizzle (bijective: nwg % 8 == 0)
    const unsigned nwg = gridDim.x * gridDim.y;
    const unsigned bid = blockIdx.y * gridDim.x + blockIdx.x;
    const unsigned sbid = (bid & 7u) * (nwg >> 3) + (bid >> 3);
    const int bn = sbid % gridDim.x;
    const int bm = sbid / gridDim.x;

    const int wm = (wave >> 1) * 64;     // 0,64,128,192
    const int wn = (wave & 1) * 64;      // 0,64

    const unsigned short* Ablk = A  + (size_t)(bm * 256) * K;
    const unsigned short* Bblk = Bt + (size_t)(bn * 128) * K;

    const int lc  = lane & 15;
    const int rl4 = lane >> 4;                     // 0..3
    const int srow = lane >> 3;                    // 0..7
    const int sgc  = ((lane & 7) ^ srow) << 3;     // pre-swizzled src chunk (elems)

    f32x4 acc[4][4] = {};
    const int nt = K >> 6;

    unsigned short *Ac = lds3[0], *An = lds3[1], *Asp = lds3[2];

    // stage half 1: A rows [wave*32, +16), B rows [wave*16, +8)
    #define STG_P1(k0, D) {                                                    \
        _Pragma("unroll")                                                      \
        for (int i = 0; i < 2; ++i) {                                          \
            const int ra = wave * 32 + i * 8 + srow;                           \
            __builtin_amdgcn_global_load_lds(                                  \
                AS1(Ablk + (size_t)ra * K + (k0) + sgc),                       \
                AS3((D) + (wave * 32 + i * 8) * 64), 16, 0, 0);                \
        }                                                                      \
        {                                                                      \
            const int rb = wave * 16 + srow;                                   \
            __builtin_amdgcn_global_load_lds(                                  \
                AS1(Bblk + (size_t)rb * K + (k0) + sgc),                       \
                AS3((D) + BOFF + (wave * 16) * 64), 16, 0, 0);                 \
        } }
    // stage half 2: A rows [wave*32+16, +16), B rows [wave*16+8, +8)
    #define STG_P2(k0, D) {                                                    \
        _Pragma("unroll")                                                      \
        for (int i = 2; i < 4; ++i) {                                          \
            const int ra = wave * 32 + i * 8 + srow;                           \
            __builtin_amdgcn_global_load_lds(                                  \
                AS1(Ablk + (size_t)ra * K + (k0) + sgc),                       \
                AS3((D) + (wave * 32 + i * 8) * 64), 16, 0, 0);                \
        }                                                                      \
        {                                                                      \
            const int rb = wave * 16 + 8 + srow;                               \
            __builtin_amdgcn_global_load_lds(                                  \
                AS1(Bblk + (size_t)rb * K + (k0) + sgc),                       \
                AS3((D) + BOFF + (wave * 16 + 8) * 64), 16, 0, 0);             \
        } }

    // prologue: stage tiles 0 and 1 (12 loads outstanding)
    STG_P1(0, Ac);  STG_P2(0, Ac);
    STG_P1(64, An); STG_P2(64, An);

    for (int t = 0; t < nt; ++t) {
        // wait for tile t (oldest 6); keep tile t+1's 6 in flight
        if (t < nt - 1) { GB_WAITV(6); } else { GB_WAITV(0); }
        __builtin_amdgcn_s_barrier();

        const bool pf = (t + 2 < nt);
        const int kpf = (t + 2) << 6;

        // ---- phase 1: issue prefetch half, a-frags + b-half0, 16 MFMA ----
        if (pf) STG_P1(kpf, Asp);
        bf16x8 a[4][2], b[2][2];
        #pragma unroll
        for (int mt = 0; mt < 4; ++mt)
            #pragma unroll
            for (int kk = 0; kk < 2; ++kk)
                a[mt][kk] = *(const bf16x8*)(
                    Ac + (wm + mt * 16 + lc) * 64 + (((kk * 4 + rl4) ^ (lc & 7)) << 3));
        #pragma unroll
        for (int n2 = 0; n2 < 2; ++n2)
            #pragma unroll
            for (int kk = 0; kk < 2; ++kk)
                b[n2][kk] = *(const bf16x8*)(
                    Ac + BOFF + (wn + n2 * 16 + lc) * 64 + (((kk * 4 + rl4) ^ (lc & 7)) << 3));
        __builtin_amdgcn_s_setprio(1);
        #pragma unroll
        for (int mt = 0; mt < 4; ++mt)
            #pragma unroll
            for (int n2 = 0; n2 < 2; ++n2)
                #pragma unroll
                for (int kk = 0; kk < 2; ++kk)
                    acc[mt][n2] = __builtin_amdgcn_mfma_f32_16x16x32_bf16(
                        a[mt][kk], b[n2][kk], acc[mt][n2], 0, 0, 0);
        __builtin_amdgcn_s_setprio(0);

        // ---- phase 2: issue prefetch half, b-half1, 16 MFMA ----
        if (pf) STG_P2(kpf, Asp);
        #pragma unroll
        for (int n2 = 0; n2 < 2; ++n2)
            #pragma unroll
            for (int kk = 0; kk < 2; ++kk)
                b[n2][kk] = *(const bf16x8*)(
                    Ac + BOFF + (wn + 32 + n2 * 16 + lc) * 64 + (((kk * 4 + rl4) ^ (lc & 7)) << 3));
        __builtin_amdgcn_s_setprio(1);
        #pragma unroll
        for (int mt = 0; mt < 4; ++mt)
            #pragma unroll
            for (int n2 = 0; n2 < 2; ++n2)
                #pragma unroll
                for (int kk = 0; kk < 2; ++kk)
                    acc[mt][2 + n2] = __builtin_amdgcn_mfma_f32_16x16x32_bf16(
                        a[mt][kk], b[n2][kk], acc[mt][2 + n2], 0, 0, 0);
        __builtin_amdgcn_s_setprio(0);

        // rotate buffers: consumed -> spare
        unsigned short* tmp = Ac; Ac = An; An = Asp; Asp = tmp;
    }

    #undef STG_P1
    #undef STG_P2

    // Epilogue. C/D frag: col = lane&15, row = (lane>>4)*4 + reg  [m89]
    const int cm0 = bm * 256 + wm;
    const int cn0 = bn * 128 + wn;
    const int lr = (lane >> 4) * 4;

    if (MODE == 0) {
        #pragma unroll
        for (int j = 0; j < 4; ++j) {
            float bv = bias[cn0 + j * 16 + lc];
            #pragma unroll
            for (int mt = 0; mt < 4; ++mt)
                #pragma unroll
                for (int r = 0; r < 4; ++r) {
                    float v = fmaxf(acc[mt][j][r] + bv, 0.0f);
                    size_t idx = (size_t)(cm0 + mt * 16 + lr + r) * N + cn0 + j * 16 + lc;
                    Cbf[idx] = f2bf(v);
                }
        }
    } else {
        float bv[4], w3v[4];
        #pragma unroll
        for (int j = 0; j < 4; ++j) {
            bv[j]  = bias[cn0 + j * 16 + lc];
            w3v[j] = w3[cn0 + j * 16 + lc];
        }
        #pragma unroll
        for (int mt = 0; mt < 4; ++mt)
            #pragma unroll
            for (int r = 0; r < 4; ++r) {
                float p = 0.0f;
                #pragma unroll
                for (int j = 0; j < 4; ++j)
                    p += fmaxf(acc[mt][j][r] + bv[j], 0.0f) * w3v[j];
                p += __shfl_xor(p, 1);
                p += __shfl_xor(p, 2);
                p += __shfl_xor(p, 4);
                p += __shfl_xor(p, 8);
                if (lc == 0)
                    atomicAdd(&scores[cm0 + mt * 16 + lr + r], p);
            }
    }
}

// ---------------------------------------------------------------------------
// Fused finalize + rank count, 2-D tiled (unchanged).
// ---------------------------------------------------------------------------
__global__ __launch_bounds__(256) void rank_count(
    const float* __restrict__ sc, const float* __restrict__ b3,
    float* __restrict__ out_scores, int* __restrict__ posg)
{
    __shared__ unsigned long long kj[256];
    const int t = threadIdx.x;
    const int bi = blockIdx.x, bj = blockIdx.y;
    const int i = bi * 256 + t;
    const float b3v = b3[0];

    {
        int j = bj * 256 + t;
        kj[t] = sort_key(sc[j] + b3v, j);
    }
    float vi = sc[i] + b3v;
    if (bj == 0) out_scores[i] = vi;
    const unsigned long long mykey = sort_key(vi, i);
    __syncthreads();

    int cnt = 0;
    #pragma unroll 32
    for (int j = 0; j < 256; ++j)
        cnt += (kj[j] < mykey) ? 1 : 0;
    atomicAdd(&posg[i], cnt);
}

// ---------------------------------------------------------------------------
// PAV + fill (latency redesign, verified R1: reg-chunk PAV + tree merge).
// ---------------------------------------------------------------------------
__global__ __launch_bounds__(1024) void pav_fill(
    const float* __restrict__ scores, const float* __restrict__ b3,
    const int* __restrict__ posg, float* __restrict__ rank_out)
{
    constexpr int n = 4096;
    __shared__ __align__(16) unsigned char lds[32768 + 16384 + 8192 + 512];
    double* bsum           = (double*)lds;                     // [4096]
    float*  svals          = (float*)(lds + 32768);            // [4096]
    unsigned short* bstart = (unsigned short*)(lds + 49152);   // [4096]
    unsigned short* cnt    = (unsigned short*)(lds + 57344);   // [256]

    const int tid = threadIdx.x;
    const float b3v = b3[0];

    // ---- scatter scores into sorted order (vectorized, 4/thread) ----
    {
        const int t = tid << 2;
        int4 p4 = *(const int4*)(posg + t);
        float4 s4 = *(const float4*)(scores + t);
        svals[p4.x] = s4.x + b3v;
        svals[p4.y] = s4.y + b3v;
        svals[p4.z] = s4.z + b3v;
        svals[p4.w] = s4.w + b3v;
    }
    __syncthreads();

    // ---- Phase A: per-lane PAV on 16-element chunks, 256 lanes ----
    if (tid < 256) {
        const int base = tid << 4;
        float vv[16];
        *(float4*)(vv + 0)  = *(const float4*)(svals + base + 0);
        *(float4*)(vv + 4)  = *(const float4*)(svals + base + 4);
        *(float4*)(vv + 8)  = *(const float4*)(svals + base + 8);
        *(float4*)(vv + 12) = *(const float4*)(svals + base + 12);
        int sp = 0;
        double tsum = 0.0; int tstart = 0;
        #pragma unroll
        for (int s = 0; s < 16; ++s) {
            const int i = base + s;
            double csum = (double)vv[s] - (double)(n - i);
            int cs = i;
            const int ce = i + 1;
            while (sp > 0 &&
                   tsum * (double)(ce - cs) <= csum * (double)(cs - tstart)) {
                csum += tsum; cs = tstart; --sp;
                if (sp > 0) { tsum = bsum[base + sp - 1]; tstart = bstart[base + sp - 1]; }
            }
            bsum[base + sp] = csum;                 // write-through push
            bstart[base + sp] = (unsigned short)cs;
            tsum = csum; tstart = cs; ++sp;
        }
        cnt[tid] = (unsigned short)sp;
    }
    __syncthreads();

    // ---- Phase B: tree merge, 8 rounds ----
    #pragma unroll 1
    for (int r = 0; r < 8; ++r) {
        const int m = 128 >> r;
        if (tid < m) {
            const int W  = 16 << r;
            const int L  = tid * (W << 1);    // left element/slot base
            const int Rb = L + W;             // right base
            int sp = cnt[L >> 4];
            const int cr = cnt[Rb >> 4];
            double tsum = bsum[L + sp - 1];
            int tstart = bstart[L + sp - 1];
            for (int j = 0; j < cr; ++j) {
                double csum = bsum[Rb + j];
                int cs = (int)bstart[Rb + j];
                const int ce = (j + 1 < cr) ? (int)bstart[Rb + j + 1] : (Rb + W);
                while (sp > 0 &&
                       tsum * (double)(ce - cs) <= csum * (double)(cs - tstart)) {
                    csum += tsum; cs = tstart; --sp;
                    if (sp > 0) { tsum = bsum[L + sp - 1]; tstart = bstart[L + sp - 1]; }
                }
                bsum[L + sp] = csum;
                bstart[L + sp] = (unsigned short)cs;
                tsum = csum; tstart = cs; ++sp;
            }
            cnt[L >> 4] = (unsigned short)sp;
        }
        __syncthreads();
    }

    // ---- gather: rank[t] = svals[p] - mean(block(p)), coalesced f4 writes ----
    const int nb = (int)cnt[0];
    {
        const int t = tid << 2;
        int4 p4 = *(const int4*)(posg + t);
        float4 o;
        int pa[4] = { p4.x, p4.y, p4.z, p4.w };
        float oa[4];
        #pragma unroll
        for (int e = 0; e < 4; ++e) {
            const int p = pa[e];
            int lo = 0, hi = nb - 1;
            while (lo < hi) {
                int mid = (lo + hi + 1) >> 1;
                if ((int)bstart[mid] <= p) lo = mid; else hi = mid - 1;
            }
            const int bs = (int)bstart[lo];
            const int be = (lo + 1 < nb) ? (int)bstart[lo + 1] : n;
            oa[e] = svals[p] - (float)(bsum[lo] / (double)(be - bs));
        }
        o.x = oa[0]; o.y = oa[1]; o.z = oa[2]; o.w = oa[3];
        *(float4*)(rank_out + t) = o;
    }
}

// ---------------------------------------------------------------------------
extern "C" void kernel_launch(void* const* d_in, const int* in_sizes, int n_in,
                              void* d_out, int out_size, void* d_ws, size_t ws_size,
                              hipStream_t stream) {
    const float* x  = (const float*)d_in[0];
    const float* W1 = (const float*)d_in[1];
    const float* b1 = (const float*)d_in[2];
    const float* W2 = (const float*)d_in[3];
    const float* b2 = (const float*)d_in[4];
    const float* W3 = (const float*)d_in[5];
    const float* b3 = (const float*)d_in[6];
    float* out = (float*)d_out;   // [0,4096): rank, [4096,8192): scores

    const int B = 4096, D_IN = 512, H = 2048;

    char* ws = (char*)d_ws;
    unsigned short* h1  = (unsigned short*)(ws);                    // 16 MB bf16
    unsigned short* xb  = (unsigned short*)(ws + (16u << 20));      //  4 MB bf16
    unsigned short* W1t = (unsigned short*)(ws + (20u << 20));      //  2 MB bf16 [N,K]
    unsigned short* W2t = (unsigned short*)(ws + (22u << 20));      //  8 MB bf16 [N,K]
    float*          sc  = (float*)(ws + (30u << 20));               // 16 KB
    int*            posg= (int*)(ws + (30u << 20) + 16384);         // 16 KB

    // 1) fused prep: convert x, transpose W1/W2, zero sc+posg.
    prep_all<<<2305, 256, 0, stream>>>(x, xb, W1, W1t, W2, W2t, sc, posg);

    // 2) GEMM1: h1 = relu(x @ W1 + b1), bf16. M=4096 N=2048 K=512.
    gemm_bf16_mfma<0><<<dim3(H / 128, B / 256), 512, 0, stream>>>(
        xb, W1t, b1, h1, nullptr, nullptr, B, H, D_IN);
    // 3) GEMM2 fused with layer-3: scores += relu(h1@W2+b2) @ W3.
    gemm_bf16_mfma<1><<<dim3(H / 128, B / 256), 512, 0, stream>>>(
        h1, W2t, b2, nullptr, W3, sc, B, H, H);

    // 4) fused finalize + rank count (256 blocks, keys from sc in-block).
    rank_count<<<dim3(B / 256, B / 256), 256, 0, stream>>>(sc, b3, out + B, posg);
    // 5) PAV + fill.
    pav_fill<<<1, 1024, 0, stream>>>(sc, b3, posg, out);
}